// Round 15
// baseline (427.898 us; speedup 1.0000x reference)
//
#include <hip/hip_runtime.h>
#include <float.h>

#define NPTS 8192
#define NB 4
#define NQ 8192

using frag_ab = __attribute__((ext_vector_type(8))) short;   // 8 bf16 (4 VGPRs)
using f32x4   = __attribute__((ext_vector_type(4))) float;

// ---------- monotone float<->uint key for atomic max over floats ----------
__device__ __forceinline__ unsigned fkey(float f) {
  unsigned u = __float_as_uint(f);
  return (u & 0x80000000u) ? ~u : (u | 0x80000000u);
}
__device__ __forceinline__ float funkey(unsigned k) {
  unsigned u = (k & 0x80000000u) ? (k & 0x7fffffffu) : ~k;
  return __uint_as_float(u);
}
__device__ __forceinline__ unsigned short bf16rn(float f) {
  unsigned u = __float_as_uint(f);
  return (unsigned short)((u + 0x7fffu + ((u >> 16) & 1u)) >> 16);
}

// sorted-insert network for top-3 smallest (values only)
#define NET3(e, k0, k1, k2)                                           \
  {                                                                   \
    float nk2 = __builtin_amdgcn_fmed3f(k2, k1, (e));                 \
    float nk1 = __builtin_amdgcn_fmed3f(k1, k0, (e));                 \
    k0 = fminf(k0, (e));                                              \
    k1 = nk1; k2 = nk2;                                               \
  }

// lexicographic (d, idx) top-3 insert — order-invariant, matches np.top_k ties
#define LEXINS(d, n, D0, D1, D2, I0, I1, I2)                          \
  if (d < D2 || (d == D2 && n < I2)) {                                \
    if (d < D1 || (d == D1 && n < I1)) {                              \
      D2 = D1; I2 = I1;                                               \
      if (d < D0 || (d == D0 && n < I0)) { D1 = D0; I1 = I0; D0 = d; I0 = n; } \
      else { D1 = d; I1 = n; }                                        \
    } else { D2 = d; I2 = n; }                                        \
  }

// K-major slab layout: element (m,k) of an [M][K] bf16 tensor lives at
// ushort index ((k>>3)*M + m)*8 + (k&7). A 16-lane MFMA fragment load is
// 4 x 256 B contiguous -> no cache-line splits.

// ---------- prep: pack pts4 + G1/G2 -> bf16 K-major slabs + init gmax ----------
__global__ __launch_bounds__(256) void k_prep(const float* __restrict__ pc,
    const float* __restrict__ G1, const float* __restrict__ G2,
    float4* __restrict__ pts4, unsigned short* __restrict__ G1KM,
    unsigned short* __restrict__ G2KM, unsigned* __restrict__ gmaxK) {
  int id = blockIdx.x * 256 + threadIdx.x;
  if (id < 32768) {
    int b = id >> 13, n = id & 8191;
    const float* pb = pc + (size_t)b * 3 * NPTS;
    float x = pb[n], y = pb[NPTS + n], z = pb[2 * NPTS + n];
    pts4[id] = make_float4(x, y, z, fmaf(x, x, fmaf(y, y, z * z)));
  } else if (id < 65536) {
    int i = id - 32768;                      // G2: [1024][256] -> 32 slabs
    int n = i & 1023, slab = i >> 10;
    const float* src = G2 + (size_t)n * 256 + slab * 8;
    float4 v0 = *(const float4*)src, v1 = *(const float4*)(src + 4);
    uint4 pk;
    pk.x = (unsigned)bf16rn(v0.x) | ((unsigned)bf16rn(v0.y) << 16);
    pk.y = (unsigned)bf16rn(v0.z) | ((unsigned)bf16rn(v0.w) << 16);
    pk.z = (unsigned)bf16rn(v1.x) | ((unsigned)bf16rn(v1.y) << 16);
    pk.w = (unsigned)bf16rn(v1.z) | ((unsigned)bf16rn(v1.w) << 16);
    *(uint4*)(G2KM + ((size_t)slab * 1024 + n) * 8) = pk;
  } else if (id < 69632) {
    int i = id - 65536;                      // G1: [256][128] -> 16 slabs
    int n = i & 255, slab = i >> 8;
    const float* src = G1 + (size_t)n * 128 + slab * 8;
    float4 v0 = *(const float4*)src, v1 = *(const float4*)(src + 4);
    uint4 pk;
    pk.x = (unsigned)bf16rn(v0.x) | ((unsigned)bf16rn(v0.y) << 16);
    pk.y = (unsigned)bf16rn(v0.z) | ((unsigned)bf16rn(v0.w) << 16);
    pk.z = (unsigned)bf16rn(v1.x) | ((unsigned)bf16rn(v1.y) << 16);
    pk.w = (unsigned)bf16rn(v1.z) | ((unsigned)bf16rn(v1.w) << 16);
    *(uint4*)(G1KM + ((size_t)slab * 256 + n) * 8) = pk;
  } else if (id < 73728) {
    gmaxK[id - 69632] = 0u;
  }
}

// ---------- fused dispatch A: knnA+idx (blocks 0..1023) || local encoder (1024..1151) ----------
// knnA now tracks top-4 VALUES (k3 via med3 identity) + top-3 INDICES
// (branchless cndmask) per (query, 256-chunk). Output layout chunk-major:
// pAf[ch][q] = float4(k0,k1,k2,k3), pIp[ch][q] = i0|i1<<8|i2<<16 (chunk-local).
__global__ __launch_bounds__(256) void k_AL(const float4* __restrict__ pts4,
    const float* __restrict__ qp, float4* __restrict__ pAf, unsigned* __restrict__ pIp,
    const float* __restrict__ pc,
    const float* __restrict__ W1, const float* __restrict__ b1,
    const float* __restrict__ W2, const float* __restrict__ b2,
    float* __restrict__ lfT, unsigned short* __restrict__ lfBKM) {
  __shared__ float sW1[192], sb1[64], sW2[8192], sb2[128];
  int bid = blockIdx.x;
  int t = threadIdx.x;

  if (bid < 1024) {
    int xb = bid & 31, ch = bid >> 5;        // ch 0..31
    int gq4 = xb * 256 + t;                  // 0..8191 (4 queries each)
    int b = xb >> 3;                         // block-uniform batch
    int qi0 = (gq4 * 4) & 8191;
    const float* qb = qp + (size_t)b * 3 * NPTS;
    float4 qx = *(const float4*)(qb + qi0);
    float4 qy = *(const float4*)(qb + NPTS + qi0);
    float4 qz = *(const float4*)(qb + 2 * NPTS + qi0);
    float tax[4] = {-2.f * qx.x, -2.f * qx.y, -2.f * qx.z, -2.f * qx.w};
    float tay[4] = {-2.f * qy.x, -2.f * qy.y, -2.f * qy.z, -2.f * qy.w};
    float taz[4] = {-2.f * qz.x, -2.f * qz.y, -2.f * qz.z, -2.f * qz.w};

    const float4* P = pts4 + (b << 13) + (ch << 8);
    float k0[4], k1[4], k2[4], k3[4];
    int i0[4], i1[4], i2[4];
#pragma unroll
    for (int j = 0; j < 4; ++j) {
      k0[j] = FLT_MAX; k1[j] = FLT_MAX; k2[j] = FLT_MAX; k3[j] = FLT_MAX;
      i0[j] = 0; i1[j] = 0; i2[j] = 0;
    }

    float4 a0 = P[0], a1 = P[1], a2 = P[2], a3 = P[3];
    for (int i = 0; i < 256; i += 4) {
      int nx = (i + 4) & 255;
      float4 n0 = P[nx], n1 = P[nx + 1], n2 = P[nx + 2], n3 = P[nx + 3];
#pragma unroll
      for (int c = 0; c < 4; ++c) {
        float4 p = (c == 0) ? a0 : (c == 1) ? a1 : (c == 2) ? a2 : a3;
        int ii = i + c;
#pragma unroll
        for (int j = 0; j < 4; ++j) {
          float e = fmaf(p.x, tax[j], fmaf(p.y, tay[j], fmaf(p.z, taz[j], p.w)));
          bool lt2 = e < k2[j], lt1 = e < k1[j], lt0 = e < k0[j];
          k3[j] = __builtin_amdgcn_fmed3f(k3[j], k2[j], e);   // 4th-smallest
          float nk2 = __builtin_amdgcn_fmed3f(k2[j], k1[j], e);
          float nk1 = __builtin_amdgcn_fmed3f(k1[j], k0[j], e);
          k0[j] = fminf(k0[j], e);
          i2[j] = lt2 ? (lt1 ? i1[j] : ii) : i2[j];
          i1[j] = lt1 ? (lt0 ? i0[j] : ii) : i1[j];
          i0[j] = lt0 ? ii : i0[j];
          k1[j] = nk1; k2[j] = nk2;
        }
      }
      a0 = n0; a1 = n1; a2 = n2; a3 = n3;
    }
    int q0 = (b << 13) | ((gq4 * 4) & 8191);
#pragma unroll
    for (int j = 0; j < 4; ++j) {
      pAf[(size_t)ch * 32768 + q0 + j] = make_float4(k0[j], k1[j], k2[j], k3[j]);
      pIp[(size_t)ch * 32768 + q0 + j] =
          (unsigned)i0[j] | ((unsigned)i1[j] << 8) | ((unsigned)i2[j] << 16);
    }
  } else {
    // ---- local encoder: lfT (f32) + lfBKM (bf16 K-major slabs)
    if (t < 192) sW1[t] = W1[t];
    if (t < 64) sb1[t] = b1[t];
    if (t < 128) sb2[t] = b2[t];
    for (int i = t; i < 8192; i += 256) sW2[i] = W2[i];
    __syncthreads();

    int gid = (bid - 1024) * 256 + t;
    int b = gid >> 13;
    const float* base = pc + (size_t)b * 3 * NPTS + (gid & 8191);
    float x = base[0], y = base[NPTS], z = base[2 * NPTS];

    float h[64];
#pragma unroll
    for (int j = 0; j < 64; ++j) {
      float v = fmaf(sW1[j * 3 + 2], z, fmaf(sW1[j * 3 + 1], y, fmaf(sW1[j * 3], x, sb1[j])));
      h[j] = fmaxf(v, 0.f);
    }

    float* o = lfT + (size_t)gid * 128;
    for (int c8 = 0; c8 < 128; c8 += 8) {
      float rr[8];
#pragma unroll
      for (int cs = 0; cs < 8; cs += 4) {
        int c = c8 + cs;
        float a0 = sb2[c], a1 = sb2[c + 1], a2 = sb2[c + 2], a3 = sb2[c + 3];
#pragma unroll
        for (int j = 0; j < 64; j += 4) {
          float4 w0 = *(const float4*)&sW2[(c + 0) * 64 + j];
          float4 w1 = *(const float4*)&sW2[(c + 1) * 64 + j];
          float4 w2 = *(const float4*)&sW2[(c + 2) * 64 + j];
          float4 w3 = *(const float4*)&sW2[(c + 3) * 64 + j];
          a0 = fmaf(w0.x, h[j], fmaf(w0.y, h[j + 1], fmaf(w0.z, h[j + 2], fmaf(w0.w, h[j + 3], a0))));
          a1 = fmaf(w1.x, h[j], fmaf(w1.y, h[j + 1], fmaf(w1.z, h[j + 2], fmaf(w1.w, h[j + 3], a1))));
          a2 = fmaf(w2.x, h[j], fmaf(w2.y, h[j + 1], fmaf(w2.z, h[j + 2], fmaf(w2.w, h[j + 3], a2))));
          a3 = fmaf(w3.x, h[j], fmaf(w3.y, h[j + 1], fmaf(w3.z, h[j + 2], fmaf(w3.w, h[j + 3], a3))));
        }
        rr[cs + 0] = fmaxf(a0, 0.f); rr[cs + 1] = fmaxf(a1, 0.f);
        rr[cs + 2] = fmaxf(a2, 0.f); rr[cs + 3] = fmaxf(a3, 0.f);
        float4 rv = make_float4(rr[cs], rr[cs + 1], rr[cs + 2], rr[cs + 3]);
        *(float4*)&o[c] = rv;
      }
      uint4 pk;
      pk.x = (unsigned)bf16rn(rr[0]) | ((unsigned)bf16rn(rr[1]) << 16);
      pk.y = (unsigned)bf16rn(rr[2]) | ((unsigned)bf16rn(rr[3]) << 16);
      pk.z = (unsigned)bf16rn(rr[4]) | ((unsigned)bf16rn(rr[5]) << 16);
      pk.w = (unsigned)bf16rn(rr[6]) | ((unsigned)bf16rn(rr[7]) << 16);
      *(uint4*)(lfBKM + ((size_t)(c8 >> 3) * 32768 + gid) * 8) = pk;   // slab write, coalesced
    }
  }
}

// ---------- fused dispatch B: genc v3 (blocks 0..511) || knnC exact (512..575) ----------
// knnC: tau = merged f32 3rd + 1e-3 (band 3e-5, 30x margin). A true-top-3
// candidate outside its chunk's f32 top-3 forces chunk k3 <= tau -> flagged
// chunk fully rescanned (P ~ 0). Otherwise exact f64 on stored indices with
// val <= tau. Lexicographic (e64, idx) => identical ids to rounds 11-14.
__global__ __launch_bounds__(512, 2) void k_GC(
    const unsigned short* __restrict__ lfBKM,
    const unsigned short* __restrict__ G1KM, const float* __restrict__ g1bias,
    const unsigned short* __restrict__ G2KM, unsigned* __restrict__ gmaxK,
    const float4* __restrict__ pts4, const float* __restrict__ qp,
    const float4* __restrict__ pAf, const unsigned* __restrict__ pIp,
    int* __restrict__ ids) {
  __shared__ char g1c[64 * 512];   // genc: [64 rows][256 bf16 cols], XOR-swizzled
  int t = threadIdx.x;
  int bid = blockIdx.x;

  if (bid >= 512) {
    // ---- knnC
    int q = (bid - 512) * 512 + t;           // 0..32767
    int b = q >> 13, qi = q & 8191;
    const float* qb = qp + (size_t)b * 3 * NPTS;
    float qx = qb[qi], qy = qb[NPTS + qi], qz = qb[2 * NPTS + qi];
    float tax = -2.f * qx, tay = -2.f * qy, taz = -2.f * qz;
    double tax64 = -2.0 * (double)qx, tay64 = -2.0 * (double)qy, taz64 = -2.0 * (double)qz;

    // pass 1: tau from merged f32 top-3
    float K0 = FLT_MAX, K1 = FLT_MAX, K2 = FLT_MAX;
    for (int ch = 0; ch < 32; ++ch) {
      float4 v = pAf[(size_t)ch * 32768 + q];
      NET3(v.x, K0, K1, K2); NET3(v.y, K0, K1, K2); NET3(v.z, K0, K1, K2);
    }
    float tau = K2 + 1e-3f;

    // pass 2: exact f64 on survivors
    double d0 = 1e300, d1 = 1e300, d2v = 1e300;
    int j0 = 0x7fffffff, j1 = 0x7fffffff, j2 = 0x7fffffff;
    const float4* Pb = pts4 + (b << 13);
    for (int ch = 0; ch < 32; ++ch) {
      float4 v = pAf[(size_t)ch * 32768 + q];
      if (v.w <= tau) {
        // flagged chunk (4th-smallest within tau): full exact rescan
        const float4* P = Pb + (ch << 8);
        for (int c = 0; c < 256; ++c) {
          float4 p = P[c];
          float e32 = fmaf(p.x, tax, fmaf(p.y, tay, fmaf(p.z, taz, p.w)));
          if (e32 <= tau) {
            double cx = (double)p.x, cy = (double)p.y, cz = (double)p.z;
            double pp = fma(cx, cx, fma(cy, cy, cz * cz));
            double e64 = fma(cx, tax64, fma(cy, tay64, fma(cz, taz64, pp)));
            int n = (ch << 8) + c;
            LEXINS(e64, n, d0, d1, d2v, j0, j1, j2);
          }
        }
      } else {
        unsigned pk = pIp[(size_t)ch * 32768 + q];
        float vals[3] = {v.x, v.y, v.z};
#pragma unroll
        for (int r = 0; r < 3; ++r) {
          if (vals[r] <= tau) {
            int n = (ch << 8) + (int)((pk >> (8 * r)) & 255u);
            float4 p = Pb[n];
            double cx = (double)p.x, cy = (double)p.y, cz = (double)p.z;
            double pp = fma(cx, cx, fma(cy, cy, cz * cz));
            double e64 = fma(cx, tax64, fma(cy, tay64, fma(cz, taz64, pp)));
            LEXINS(e64, n, d0, d1, d2v, j0, j1, j2);
          }
        }
      }
    }
    ids[q * 4 + 0] = j0; ids[q * 4 + 1] = j1; ids[q * 4 + 2] = j2;
    return;
  }

  // ---- genc v3 (verbatim)
  int gb = bid;
  int w = t >> 6, l = t & 63, lr = l & 15, lg = l >> 4;
  int mBase = gb * 64;

  // phase 1: wave w computes tile (rb=w&3 rows x16, cols (w>>2)*128..+127) of g1
  int rb = w & 3, cbg = w >> 2;
  int m = mBase + rb * 16 + lr;
  f32x4 acc1[8] = {};
#pragma unroll
  for (int ko = 0; ko < 4; ++ko) {
    frag_ab yf = *(const frag_ab*)(lfBKM + ((size_t)(ko * 4 + lg) * 32768 + m) * 8);
#pragma unroll
    for (int i = 0; i < 8; ++i) {
      int cb = cbg * 8 + i;
      frag_ab xf = *(const frag_ab*)(G1KM + ((size_t)(ko * 4 + lg) * 256 + cb * 16 + lr) * 8);
      acc1[i] = __builtin_amdgcn_mfma_f32_16x16x32_bf16(xf, yf, acc1[i], 0, 0, 0);
    }
  }
  {
    int mloc = rb * 16 + lr;
    unsigned swz = (unsigned)((mloc & 7) << 4);
#pragma unroll
    for (int i = 0; i < 8; ++i) {
      int n0 = (cbg * 8 + i) * 16 + lg * 4;
      float4 bs = *(const float4*)(g1bias + n0);
      unsigned short p0 = bf16rn(fmaxf(acc1[i][0] + bs.x, 0.f));
      unsigned short p1 = bf16rn(fmaxf(acc1[i][1] + bs.y, 0.f));
      unsigned short p2 = bf16rn(fmaxf(acc1[i][2] + bs.z, 0.f));
      unsigned short p3 = bf16rn(fmaxf(acc1[i][3] + bs.w, 0.f));
      uint2 pk;
      pk.x = (unsigned)p0 | ((unsigned)p1 << 16);
      pk.y = (unsigned)p2 | ((unsigned)p3 << 16);
      unsigned off = (unsigned)(mloc * 512) + (((unsigned)(n0 * 2)) ^ swz);
      *(uint2*)(g1c + off) = pk;
    }
  }
  __syncthreads();

  // phase 2: wave w owns output cols w*128..+127; A-frags in registers
  frag_ab a[4][8];
#pragma unroll
  for (int mb = 0; mb < 4; ++mb) {
    int row = mb * 16 + lr;
    unsigned sz = (unsigned)((row & 7) << 4);
#pragma unroll
    for (int ks = 0; ks < 8; ++ks)
      a[mb][ks] = *(const frag_ab*)(g1c + row * 512 + (((unsigned)(ks * 64 + lg * 16)) ^ sz));
  }
  int bIdx = gb >> 7;
#pragma unroll 2
  for (int cb2 = 0; cb2 < 8; ++cb2) {
    int n = w * 128 + cb2 * 16 + lr;
    f32x4 c0 = {}, c1 = {}, c2 = {}, c3 = {};
#pragma unroll
    for (int ks = 0; ks < 8; ++ks) {
      frag_ab yf = *(const frag_ab*)(G2KM + ((size_t)(ks * 4 + lg) * 1024 + n) * 8);
      c0 = __builtin_amdgcn_mfma_f32_16x16x32_bf16(a[0][ks], yf, c0, 0, 0, 0);
      c1 = __builtin_amdgcn_mfma_f32_16x16x32_bf16(a[1][ks], yf, c1, 0, 0, 0);
      c2 = __builtin_amdgcn_mfma_f32_16x16x32_bf16(a[2][ks], yf, c2, 0, 0, 0);
      c3 = __builtin_amdgcn_mfma_f32_16x16x32_bf16(a[3][ks], yf, c3, 0, 0, 0);
    }
    float v = fmaxf(fmaxf(fmaxf(c0[0], c0[1]), fmaxf(c0[2], c0[3])),
                    fmaxf(fmaxf(c1[0], c1[1]), fmaxf(c1[2], c1[3])));
    v = fmaxf(v, fmaxf(fmaxf(fmaxf(c2[0], c2[1]), fmaxf(c2[2], c2[3])),
                       fmaxf(fmaxf(c3[0], c3[1]), fmaxf(c3[2], c3[3]))));
    v = fmaxf(v, __shfl_xor(v, 16));
    v = fmaxf(v, __shfl_xor(v, 32));
    if (lg == 0) atomicMax(&gmaxK[bIdx * 1024 + n], fkey(v));
  }
}

// ---------- fused output: bcast gmax+bias (ch<1024) + gather (ch 1024..1151) ----------
__global__ __launch_bounds__(256) void k_out(const unsigned* __restrict__ gmaxK,
    const float* __restrict__ g2bias, const float* __restrict__ lfT,
    const int* __restrict__ ids, float* __restrict__ out) {
  int bid = blockIdx.x;
  int t = threadIdx.x;
  if (bid < 32768) {
    int id = bid * 256 + t;                  // float4 index
    int m4 = id & 2047;
    int c = (id >> 11) & 1023;
    int b = id >> 21;
    float v = funkey(gmaxK[b * 1024 + c]) + g2bias[c];
    *(float4*)(out + ((size_t)(b * 1152 + c) << 13) + (m4 << 2)) = make_float4(v, v, v, v);
  } else {
    int bid2 = bid - 32768;
    int b = bid2 >> 7, mb = bid2 & 127;
    int m = mb * 64 + (t & 63);
    int cg = t >> 6;
    int q = b * NQ + m;
    int ia = ids[q * 4 + 0], ib = ids[q * 4 + 1], ic = ids[q * 4 + 2];
    const float* f0 = lfT + ((size_t)b * NPTS + ia) * 128;
    const float* f1 = lfT + ((size_t)b * NPTS + ib) * 128;
    const float* f2 = lfT + ((size_t)b * NPTS + ic) * 128;
    float* ob = out + ((size_t)(b * 1152 + 1024)) * (size_t)NQ + m;
    const float s = 1.f / 3.f;
#pragma unroll
    for (int c4 = 0; c4 < 32; c4 += 4) {
      int c = cg * 32 + c4;
      float4 v0 = *(const float4*)(f0 + c);
      float4 v1 = *(const float4*)(f1 + c);
      float4 v2 = *(const float4*)(f2 + c);
      ob[(size_t)(c + 0) * NQ] = ((v0.x + v1.x) + v2.x) * s;
      ob[(size_t)(c + 1) * NQ] = ((v0.y + v1.y) + v2.y) * s;
      ob[(size_t)(c + 2) * NQ] = ((v0.z + v1.z) + v2.z) * s;
      ob[(size_t)(c + 3) * NQ] = ((v0.w + v1.w) + v2.w) * s;
    }
  }
}

extern "C" void kernel_launch(void* const* d_in, const int* in_sizes, int n_in,
                              void* d_out, int out_size, void* d_ws, size_t ws_size,
                              hipStream_t stream) {
  const float* pc  = (const float*)d_in[0];
  const float* qp  = (const float*)d_in[1];
  const float* W1  = (const float*)d_in[2];
  const float* b1  = (const float*)d_in[3];
  const float* W2  = (const float*)d_in[4];
  const float* b2  = (const float*)d_in[5];
  const float* G1  = (const float*)d_in[6];
  const float* g1b = (const float*)d_in[7];
  const float* G2  = (const float*)d_in[8];
  const float* g2b = (const float*)d_in[9];
  float* out = (float*)d_out;

  char* ws = (char*)d_ws;
  float*          lfT   = (float*)(ws + 0);                  // 16 MB [B][N][128] f32
  float4*         pAf   = (float4*)(ws + 16777216);          // 16.78 MB [32 ch][32768 q]
  unsigned*       pIp   = (unsigned*)(ws + 33554432);        // 4.19 MB  [32 ch][32768 q]
  unsigned short* lfBKM = (unsigned short*)(ws + 37748736);  // 8 MB (16 slabs x 32768)
  int*            ids   = (int*)(ws + 46137344);             // 512 KB
  float4*         pts4  = (float4*)(ws + 46661632);          // 512 KB
  unsigned short* G1KM  = (unsigned short*)(ws + 47185920);  // 64 KB  (16 slabs x 256)
  unsigned short* G2KM  = (unsigned short*)(ws + 47251456);  // 512 KB (32 slabs x 1024)
  unsigned*       gmaxK = (unsigned*)(ws + 47775744);        // 16 KB -> end ~47.8 MB

  k_prep<<<288, 256, 0, stream>>>(pc, G1, G2, pts4, G1KM, G2KM, gmaxK);
  k_AL<<<1152, 256, 0, stream>>>(pts4, qp, pAf, pIp, pc, W1, b1, W2, b2, lfT, lfBKM);
  k_GC<<<576, 512, 0, stream>>>(lfBKM, G1KM, g1b, G2KM, gmaxK, pts4, qp, pAf, pIp, ids);
  k_out<<<33280, 256, 0, stream>>>(gmaxK, g2b, lfT, ids, out);
}

// Round 16
// 261.991 us; speedup vs baseline: 1.6333x; 1.6333x over previous
//
#include <hip/hip_runtime.h>
#include <float.h>

#define NPTS 8192
#define NB 4
#define NQ 8192

using frag_ab = __attribute__((ext_vector_type(8))) short;   // 8 bf16 (4 VGPRs)
using f32x4   = __attribute__((ext_vector_type(4))) float;

// ---------- monotone float<->uint key for atomic max over floats ----------
__device__ __forceinline__ unsigned fkey(float f) {
  unsigned u = __float_as_uint(f);
  return (u & 0x80000000u) ? ~u : (u | 0x80000000u);
}
__device__ __forceinline__ float funkey(unsigned k) {
  unsigned u = (k & 0x80000000u) ? (k & 0x7fffffffu) : ~k;
  return __uint_as_float(u);
}
__device__ __forceinline__ unsigned short bf16rn(float f) {
  unsigned u = __float_as_uint(f);
  return (unsigned short)((u + 0x7fffu + ((u >> 16) & 1u)) >> 16);
}

// sorted-insert network for top-3 smallest (values only)
#define NET3(e, k0, k1, k2)                                           \
  {                                                                   \
    float nk2 = __builtin_amdgcn_fmed3f(k2, k1, (e));                 \
    float nk1 = __builtin_amdgcn_fmed3f(k1, k0, (e));                 \
    k0 = fminf(k0, (e));                                              \
    k1 = nk1; k2 = nk2;                                               \
  }

// K-major slab layout: element (m,k) of an [M][K] bf16 tensor lives at
// ushort index ((k>>3)*M + m)*8 + (k&7). A 16-lane MFMA fragment load is
// 4 x 256 B contiguous -> no cache-line splits.

// ---------- prep: pack pts4 + G1/G2 -> bf16 K-major slabs + init gmax ----------
__global__ __launch_bounds__(256) void k_prep(const float* __restrict__ pc,
    const float* __restrict__ G1, const float* __restrict__ G2,
    float4* __restrict__ pts4, unsigned short* __restrict__ G1KM,
    unsigned short* __restrict__ G2KM, unsigned* __restrict__ gmaxK) {
  int id = blockIdx.x * 256 + threadIdx.x;
  if (id < 32768) {
    int b = id >> 13, n = id & 8191;
    const float* pb = pc + (size_t)b * 3 * NPTS;
    float x = pb[n], y = pb[NPTS + n], z = pb[2 * NPTS + n];
    pts4[id] = make_float4(x, y, z, fmaf(x, x, fmaf(y, y, z * z)));
  } else if (id < 65536) {
    int i = id - 32768;                      // G2: [1024][256] -> 32 slabs
    int n = i & 1023, slab = i >> 10;
    const float* src = G2 + (size_t)n * 256 + slab * 8;
    float4 v0 = *(const float4*)src, v1 = *(const float4*)(src + 4);
    uint4 pk;
    pk.x = (unsigned)bf16rn(v0.x) | ((unsigned)bf16rn(v0.y) << 16);
    pk.y = (unsigned)bf16rn(v0.z) | ((unsigned)bf16rn(v0.w) << 16);
    pk.z = (unsigned)bf16rn(v1.x) | ((unsigned)bf16rn(v1.y) << 16);
    pk.w = (unsigned)bf16rn(v1.z) | ((unsigned)bf16rn(v1.w) << 16);
    *(uint4*)(G2KM + ((size_t)slab * 1024 + n) * 8) = pk;
  } else if (id < 69632) {
    int i = id - 65536;                      // G1: [256][128] -> 16 slabs
    int n = i & 255, slab = i >> 8;
    const float* src = G1 + (size_t)n * 128 + slab * 8;
    float4 v0 = *(const float4*)src, v1 = *(const float4*)(src + 4);
    uint4 pk;
    pk.x = (unsigned)bf16rn(v0.x) | ((unsigned)bf16rn(v0.y) << 16);
    pk.y = (unsigned)bf16rn(v0.z) | ((unsigned)bf16rn(v0.w) << 16);
    pk.z = (unsigned)bf16rn(v1.x) | ((unsigned)bf16rn(v1.y) << 16);
    pk.w = (unsigned)bf16rn(v1.z) | ((unsigned)bf16rn(v1.w) << 16);
    *(uint4*)(G1KM + ((size_t)slab * 256 + n) * 8) = pk;
  } else if (id < 73728) {
    gmaxK[id - 69632] = 0u;
  }
}

// ---------- fused dispatch A: knnA (blocks 0..1023) || local encoder (1024..1151) ----------
__global__ __launch_bounds__(256) void k_AL(const float4* __restrict__ pts4,
    const float* __restrict__ qp, float* __restrict__ pA,
    const float* __restrict__ pc,
    const float* __restrict__ W1, const float* __restrict__ b1,
    const float* __restrict__ W2, const float* __restrict__ b2,
    float* __restrict__ lfT, unsigned short* __restrict__ lfBKM) {
  __shared__ float sW1[192], sb1[64], sW2[8192], sb2[128];
  int bid = blockIdx.x;
  int t = threadIdx.x;

  if (bid < 1024) {
    // ---- knnA: 4 queries/thread, branchless f32 top-3 per (query, 256-chunk)
    int xb = bid & 31, ch = bid >> 5;
    int gq4 = xb * 256 + t;                  // 0..8191
    int b = xb >> 3;                         // block-uniform batch
    int qi0 = (gq4 * 4) & 8191;
    const float* qb = qp + (size_t)b * 3 * NPTS;
    float4 qx = *(const float4*)(qb + qi0);
    float4 qy = *(const float4*)(qb + NPTS + qi0);
    float4 qz = *(const float4*)(qb + 2 * NPTS + qi0);
    float tax[4] = {-2.f * qx.x, -2.f * qx.y, -2.f * qx.z, -2.f * qx.w};
    float tay[4] = {-2.f * qy.x, -2.f * qy.y, -2.f * qy.z, -2.f * qy.w};
    float taz[4] = {-2.f * qz.x, -2.f * qz.y, -2.f * qz.z, -2.f * qz.w};

    const float4* P = pts4 + (b << 13) + (ch << 8);
    float k0[4], k1[4], k2[4];
#pragma unroll
    for (int j = 0; j < 4; ++j) { k0[j] = FLT_MAX; k1[j] = FLT_MAX; k2[j] = FLT_MAX; }

    float4 a0 = P[0], a1 = P[1], a2 = P[2], a3 = P[3];
    for (int i = 0; i < 256; i += 4) {
      int nx = (i + 4) & 255;
      float4 n0 = P[nx], n1 = P[nx + 1], n2 = P[nx + 2], n3 = P[nx + 3];
#pragma unroll
      for (int c = 0; c < 4; ++c) {
        float4 p = (c == 0) ? a0 : (c == 1) ? a1 : (c == 2) ? a2 : a3;
#pragma unroll
        for (int j = 0; j < 4; ++j) {
          float e = fmaf(p.x, tax[j], fmaf(p.y, tay[j], fmaf(p.z, taz[j], p.w)));
          NET3(e, k0[j], k1[j], k2[j]);
        }
      }
      a0 = n0; a1 = n1; a2 = n2; a3 = n3;
    }
    float* pa = pA + ((size_t)gq4 * 32 + ch) * 12;
#pragma unroll
    for (int j = 0; j < 4; ++j) {
      pa[j * 3 + 0] = k0[j]; pa[j * 3 + 1] = k1[j]; pa[j * 3 + 2] = k2[j];
    }
  } else {
    // ---- local encoder: lfT (f32) + lfBKM (bf16 K-major slabs)
    if (t < 192) sW1[t] = W1[t];
    if (t < 64) sb1[t] = b1[t];
    if (t < 128) sb2[t] = b2[t];
    for (int i = t; i < 8192; i += 256) sW2[i] = W2[i];
    __syncthreads();

    int gid = (bid - 1024) * 256 + t;
    int b = gid >> 13;
    const float* base = pc + (size_t)b * 3 * NPTS + (gid & 8191);
    float x = base[0], y = base[NPTS], z = base[2 * NPTS];

    float h[64];
#pragma unroll
    for (int j = 0; j < 64; ++j) {
      float v = fmaf(sW1[j * 3 + 2], z, fmaf(sW1[j * 3 + 1], y, fmaf(sW1[j * 3], x, sb1[j])));
      h[j] = fmaxf(v, 0.f);
    }

    float* o = lfT + (size_t)gid * 128;
    for (int c8 = 0; c8 < 128; c8 += 8) {
      float rr[8];
#pragma unroll
      for (int cs = 0; cs < 8; cs += 4) {
        int c = c8 + cs;
        float a0 = sb2[c], a1 = sb2[c + 1], a2 = sb2[c + 2], a3 = sb2[c + 3];
#pragma unroll
        for (int j = 0; j < 64; j += 4) {
          float4 w0 = *(const float4*)&sW2[(c + 0) * 64 + j];
          float4 w1 = *(const float4*)&sW2[(c + 1) * 64 + j];
          float4 w2 = *(const float4*)&sW2[(c + 2) * 64 + j];
          float4 w3 = *(const float4*)&sW2[(c + 3) * 64 + j];
          a0 = fmaf(w0.x, h[j], fmaf(w0.y, h[j + 1], fmaf(w0.z, h[j + 2], fmaf(w0.w, h[j + 3], a0))));
          a1 = fmaf(w1.x, h[j], fmaf(w1.y, h[j + 1], fmaf(w1.z, h[j + 2], fmaf(w1.w, h[j + 3], a1))));
          a2 = fmaf(w2.x, h[j], fmaf(w2.y, h[j + 1], fmaf(w2.z, h[j + 2], fmaf(w2.w, h[j + 3], a2))));
          a3 = fmaf(w3.x, h[j], fmaf(w3.y, h[j + 1], fmaf(w3.z, h[j + 2], fmaf(w3.w, h[j + 3], a3))));
        }
        rr[cs + 0] = fmaxf(a0, 0.f); rr[cs + 1] = fmaxf(a1, 0.f);
        rr[cs + 2] = fmaxf(a2, 0.f); rr[cs + 3] = fmaxf(a3, 0.f);
        float4 rv = make_float4(rr[cs], rr[cs + 1], rr[cs + 2], rr[cs + 3]);
        *(float4*)&o[c] = rv;
      }
      uint4 pk;
      pk.x = (unsigned)bf16rn(rr[0]) | ((unsigned)bf16rn(rr[1]) << 16);
      pk.y = (unsigned)bf16rn(rr[2]) | ((unsigned)bf16rn(rr[3]) << 16);
      pk.z = (unsigned)bf16rn(rr[4]) | ((unsigned)bf16rn(rr[5]) << 16);
      pk.w = (unsigned)bf16rn(rr[6]) | ((unsigned)bf16rn(rr[7]) << 16);
      *(uint4*)(lfBKM + ((size_t)(c8 >> 3) * 32768 + gid) * 8) = pk;   // slab write, coalesced
    }
  }
}

// ---------- fused dispatch B: knnB (blocks 0..255) || genc v3 (blocks 256..767) ----------
// knnB and genc are data-independent; knnB (the long pole) gets the low block
// ids so it acquires residency first. Each knnB thread recomputes its queries'
// gates inline from pA (bit-identical NET3 order to the old k_gate).
__global__ __launch_bounds__(512, 2) void k_BG(
    const unsigned short* __restrict__ lfBKM,
    const unsigned short* __restrict__ G1KM, const float* __restrict__ g1bias,
    const unsigned short* __restrict__ G2KM, unsigned* __restrict__ gmaxK,
    const float4* __restrict__ pts4, const float* __restrict__ qp,
    const float* __restrict__ pA,
    double* __restrict__ pd2, int* __restrict__ pi2) {
  __shared__ char g1c[64 * 512];   // genc: [64 rows][256 bf16 cols], XOR-swizzled
  int t = threadIdx.x;
  int bid = blockIdx.x;

  if (bid < 256) {
    // ---- knnB: gated rescan; exact f64 top-3 per (query, 512-chunk)
    int xb = bid & 15, ch = bid >> 4;        // ch 0..15
    int gq4 = xb * 512 + t;                  // 0..8191
    int b = xb >> 2;                         // block-uniform batch
    int qi0 = (gq4 * 4) & 8191;
    const float* qb = qp + (size_t)b * 3 * NPTS;
    float4 qx = *(const float4*)(qb + qi0);
    float4 qy = *(const float4*)(qb + NPTS + qi0);
    float4 qz = *(const float4*)(qb + 2 * NPTS + qi0);
    float tax[4] = {-2.f * qx.x, -2.f * qx.y, -2.f * qx.z, -2.f * qx.w};
    float tay[4] = {-2.f * qy.x, -2.f * qy.y, -2.f * qy.z, -2.f * qy.w};
    float taz[4] = {-2.f * qz.x, -2.f * qz.y, -2.f * qz.z, -2.f * qz.w};
    float qxs[4] = {qx.x, qx.y, qx.z, qx.w};
    float qys[4] = {qy.x, qy.y, qy.z, qy.w};
    float qzs[4] = {qz.x, qz.y, qz.z, qz.w};

    // inline gate: merge 32 chunk-partials per query (same op order as k_gate)
    float gt[4];
    {
      const float* pa = pA + (size_t)gq4 * 384;
#pragma unroll
      for (int j = 0; j < 4; ++j) {
        float k0 = FLT_MAX, k1 = FLT_MAX, k2 = FLT_MAX;
        for (int ch2 = 0; ch2 < 32; ++ch2) {
          float e0 = pa[ch2 * 12 + j * 3 + 0];
          float e1 = pa[ch2 * 12 + j * 3 + 1];
          float e2 = pa[ch2 * 12 + j * 3 + 2];
          NET3(e0, k0, k1, k2); NET3(e1, k0, k1, k2); NET3(e2, k0, k1, k2);
        }
        gt[j] = k2 + 1e-3f;   // f32 eval band ~3e-5; 30x margin
      }
    }

    double d0[4], d1[4], d2[4];
    int i0[4], i1[4], i2[4];
#pragma unroll
    for (int j = 0; j < 4; ++j) {
      d0[j] = 1e300; d1[j] = 1e300; d2[j] = 1e300;
      i0[j] = 0; i1[j] = 0; i2[j] = 0;
    }

    const float4* P = pts4 + (b << 13) + (ch << 9);
    int nb = ch << 9;
    float4 a0 = P[0], a1 = P[1], a2 = P[2], a3 = P[3];
    for (int i = 0; i < 512; i += 4) {
      int nx = (i + 4) & 511;
      float4 n0 = P[nx], n1 = P[nx + 1], n2 = P[nx + 2], n3 = P[nx + 3];
#pragma unroll
      for (int j = 0; j < 4; ++j) {
        float e0 = fmaf(a0.x, tax[j], fmaf(a0.y, tay[j], fmaf(a0.z, taz[j], a0.w)));
        float e1 = fmaf(a1.x, tax[j], fmaf(a1.y, tay[j], fmaf(a1.z, taz[j], a1.w)));
        float e2 = fmaf(a2.x, tax[j], fmaf(a2.y, tay[j], fmaf(a2.z, taz[j], a2.w)));
        float e3 = fmaf(a3.x, tax[j], fmaf(a3.y, tay[j], fmaf(a3.z, taz[j], a3.w)));
        float mn = fminf(fminf(e0, e1), fminf(e2, e3));
        if (mn <= gt[j]) {                      // rare
          double tax64 = -2.0 * (double)qxs[j];
          double tay64 = -2.0 * (double)qys[j];
          double taz64 = -2.0 * (double)qzs[j];
#pragma unroll
          for (int c = 0; c < 4; ++c) {
            float ec = (c == 0) ? e0 : (c == 1) ? e1 : (c == 2) ? e2 : e3;
            float4 p = (c == 0) ? a0 : (c == 1) ? a1 : (c == 2) ? a2 : a3;
            if (ec <= gt[j]) {
              double cx = (double)p.x, cy = (double)p.y, cz = (double)p.z;
              double pp = fma(cx, cx, fma(cy, cy, cz * cz));
              double e64 = fma(cx, tax64, fma(cy, tay64, fma(cz, taz64, pp)));
              int n = nb + i + c;
              if (e64 < d2[j]) {                // strict <: scan order = index order
                if (e64 < d1[j]) {
                  d2[j] = d1[j]; i2[j] = i1[j];
                  if (e64 < d0[j]) { d1[j] = d0[j]; i1[j] = i0[j]; d0[j] = e64; i0[j] = n; }
                  else { d1[j] = e64; i1[j] = n; }
                } else { d2[j] = e64; i2[j] = n; }
              }
            }
          }
        }
      }
      a0 = n0; a1 = n1; a2 = n2; a3 = n3;
    }

    double* pdq = pd2 + ((size_t)gq4 * 16 + ch) * 12;
    int* piq = pi2 + ((size_t)gq4 * 16 + ch) * 12;
#pragma unroll
    for (int j = 0; j < 4; ++j) {
      pdq[j * 3 + 0] = d0[j]; pdq[j * 3 + 1] = d1[j]; pdq[j * 3 + 2] = d2[j];
      piq[j * 3 + 0] = i0[j]; piq[j * 3 + 1] = i1[j]; piq[j * 3 + 2] = i2[j];
    }
    return;
  }

  // ---- genc v3 (round-11 verbatim, blocks shifted by 256)
  int gb = bid - 256;
  int w = t >> 6, l = t & 63, lr = l & 15, lg = l >> 4;
  int mBase = gb * 64;

  // phase 1: wave w computes tile (rb=w&3 rows x16, cols (w>>2)*128..+127) of g1
  int rb = w & 3, cbg = w >> 2;
  int m = mBase + rb * 16 + lr;
  f32x4 acc1[8] = {};
#pragma unroll
  for (int ko = 0; ko < 4; ++ko) {
    frag_ab yf = *(const frag_ab*)(lfBKM + ((size_t)(ko * 4 + lg) * 32768 + m) * 8);
#pragma unroll
    for (int i = 0; i < 8; ++i) {
      int cb = cbg * 8 + i;
      frag_ab xf = *(const frag_ab*)(G1KM + ((size_t)(ko * 4 + lg) * 256 + cb * 16 + lr) * 8);
      acc1[i] = __builtin_amdgcn_mfma_f32_16x16x32_bf16(xf, yf, acc1[i], 0, 0, 0);
    }
  }
  {
    int mloc = rb * 16 + lr;
    unsigned swz = (unsigned)((mloc & 7) << 4);
#pragma unroll
    for (int i = 0; i < 8; ++i) {
      int n0 = (cbg * 8 + i) * 16 + lg * 4;
      float4 bs = *(const float4*)(g1bias + n0);
      unsigned short p0 = bf16rn(fmaxf(acc1[i][0] + bs.x, 0.f));
      unsigned short p1 = bf16rn(fmaxf(acc1[i][1] + bs.y, 0.f));
      unsigned short p2 = bf16rn(fmaxf(acc1[i][2] + bs.z, 0.f));
      unsigned short p3 = bf16rn(fmaxf(acc1[i][3] + bs.w, 0.f));
      uint2 pk;
      pk.x = (unsigned)p0 | ((unsigned)p1 << 16);
      pk.y = (unsigned)p2 | ((unsigned)p3 << 16);
      unsigned off = (unsigned)(mloc * 512) + (((unsigned)(n0 * 2)) ^ swz);
      *(uint2*)(g1c + off) = pk;
    }
  }
  __syncthreads();

  // phase 2: wave w owns output cols w*128..+127; A-frags in registers
  frag_ab a[4][8];
#pragma unroll
  for (int mb = 0; mb < 4; ++mb) {
    int row = mb * 16 + lr;
    unsigned sz = (unsigned)((row & 7) << 4);
#pragma unroll
    for (int ks = 0; ks < 8; ++ks)
      a[mb][ks] = *(const frag_ab*)(g1c + row * 512 + (((unsigned)(ks * 64 + lg * 16)) ^ sz));
  }
  int bIdx = gb >> 7;
#pragma unroll 2
  for (int cb2 = 0; cb2 < 8; ++cb2) {
    int n = w * 128 + cb2 * 16 + lr;
    f32x4 c0 = {}, c1 = {}, c2 = {}, c3 = {};
#pragma unroll
    for (int ks = 0; ks < 8; ++ks) {
      frag_ab yf = *(const frag_ab*)(G2KM + ((size_t)(ks * 4 + lg) * 1024 + n) * 8);
      c0 = __builtin_amdgcn_mfma_f32_16x16x32_bf16(a[0][ks], yf, c0, 0, 0, 0);
      c1 = __builtin_amdgcn_mfma_f32_16x16x32_bf16(a[1][ks], yf, c1, 0, 0, 0);
      c2 = __builtin_amdgcn_mfma_f32_16x16x32_bf16(a[2][ks], yf, c2, 0, 0, 0);
      c3 = __builtin_amdgcn_mfma_f32_16x16x32_bf16(a[3][ks], yf, c3, 0, 0, 0);
    }
    float v = fmaxf(fmaxf(fmaxf(c0[0], c0[1]), fmaxf(c0[2], c0[3])),
                    fmaxf(fmaxf(c1[0], c1[1]), fmaxf(c1[2], c1[3])));
    v = fmaxf(v, fmaxf(fmaxf(fmaxf(c2[0], c2[1]), fmaxf(c2[2], c2[3])),
                       fmaxf(fmaxf(c3[0], c3[1]), fmaxf(c3[2], c3[3]))));
    v = fmaxf(v, __shfl_xor(v, 16));
    v = fmaxf(v, __shfl_xor(v, 32));
    if (lg == 0) atomicMax(&gmaxK[bIdx * 1024 + n], fkey(v));
  }
}

// ---------- KNN C: merge 16 chunk-partials (chunk order = index order, strict <) ----------
__global__ __launch_bounds__(256) void k_knnC(const double* __restrict__ pd2,
    const int* __restrict__ pi2, int* __restrict__ ids) {
  int q = blockIdx.x * 256 + threadIdx.x;
  int gq4 = q >> 2, j = q & 3;
  double d0 = 1e300, d1 = 1e300, d2v = 1e300;
  int i0 = 0, i1 = 0, i2 = 0;
  for (int ch = 0; ch < 16; ++ch) {
    const double* pdq = pd2 + ((size_t)gq4 * 16 + ch) * 12 + j * 3;
    const int* piq = pi2 + ((size_t)gq4 * 16 + ch) * 12 + j * 3;
#pragma unroll
    for (int k = 0; k < 3; ++k) {
      double d = pdq[k];
      int n = piq[k];
      if (d < d2v) {
        if (d < d1) {
          d2v = d1; i2 = i1;
          if (d < d0) { d1 = d0; i1 = i0; d0 = d; i0 = n; }
          else { d1 = d; i1 = n; }
        } else { d2v = d; i2 = n; }
      }
    }
  }
  ids[q * 4 + 0] = i0; ids[q * 4 + 1] = i1; ids[q * 4 + 2] = i2;
}

// ---------- fused output: bcast gmax+bias (ch<1024) + gather (ch 1024..1151) ----------
__global__ __launch_bounds__(256) void k_out(const unsigned* __restrict__ gmaxK,
    const float* __restrict__ g2bias, const float* __restrict__ lfT,
    const int* __restrict__ ids, float* __restrict__ out) {
  int bid = blockIdx.x;
  int t = threadIdx.x;
  if (bid < 32768) {
    int id = bid * 256 + t;                  // float4 index
    int m4 = id & 2047;
    int c = (id >> 11) & 1023;
    int b = id >> 21;
    float v = funkey(gmaxK[b * 1024 + c]) + g2bias[c];
    *(float4*)(out + ((size_t)(b * 1152 + c) << 13) + (m4 << 2)) = make_float4(v, v, v, v);
  } else {
    int bid2 = bid - 32768;
    int b = bid2 >> 7, mb = bid2 & 127;
    int m = mb * 64 + (t & 63);
    int cg = t >> 6;
    int q = b * NQ + m;
    int ia = ids[q * 4 + 0], ib = ids[q * 4 + 1], ic = ids[q * 4 + 2];
    const float* f0 = lfT + ((size_t)b * NPTS + ia) * 128;
    const float* f1 = lfT + ((size_t)b * NPTS + ib) * 128;
    const float* f2 = lfT + ((size_t)b * NPTS + ic) * 128;
    float* ob = out + ((size_t)(b * 1152 + 1024)) * (size_t)NQ + m;
    const float s = 1.f / 3.f;
#pragma unroll
    for (int c4 = 0; c4 < 32; c4 += 4) {
      int c = cg * 32 + c4;
      float4 v0 = *(const float4*)(f0 + c);
      float4 v1 = *(const float4*)(f1 + c);
      float4 v2 = *(const float4*)(f2 + c);
      ob[(size_t)(c + 0) * NQ] = ((v0.x + v1.x) + v2.x) * s;
      ob[(size_t)(c + 1) * NQ] = ((v0.y + v1.y) + v2.y) * s;
      ob[(size_t)(c + 2) * NQ] = ((v0.z + v1.z) + v2.z) * s;
      ob[(size_t)(c + 3) * NQ] = ((v0.w + v1.w) + v2.w) * s;
    }
  }
}

extern "C" void kernel_launch(void* const* d_in, const int* in_sizes, int n_in,
                              void* d_out, int out_size, void* d_ws, size_t ws_size,
                              hipStream_t stream) {
  const float* pc  = (const float*)d_in[0];
  const float* qp  = (const float*)d_in[1];
  const float* W1  = (const float*)d_in[2];
  const float* b1  = (const float*)d_in[3];
  const float* W2  = (const float*)d_in[4];
  const float* b2  = (const float*)d_in[5];
  const float* G1  = (const float*)d_in[6];
  const float* g1b = (const float*)d_in[7];
  const float* G2  = (const float*)d_in[8];
  const float* g2b = (const float*)d_in[9];
  float* out = (float*)d_out;

  char* ws = (char*)d_ws;
  // No aliasing this round (knnB and genc run concurrently in k_BG).
  float*          lfT   = (float*)(ws + 0);                  // 16 MB [B][N][128] f32
  float*          pA    = (float*)(ws + 16777216);           // 12.58 MB [8192][32][12]
  double*         pd2   = (double*)(ws + 29360128);          // 12.58 MB [8192][16][12] f64
  int*            pi2   = (int*)(ws + 41943040);             // 6.29 MB
  unsigned short* lfBKM = (unsigned short*)(ws + 48234496);  // 8 MB (16 slabs x 32768)
  int*            ids   = (int*)(ws + 56623104);             // 512 KB
  float4*         pts4  = (float4*)(ws + 57147392);          // 512 KB
  unsigned short* G1KM  = (unsigned short*)(ws + 57671680);  // 64 KB  (16 slabs x 256)
  unsigned short* G2KM  = (unsigned short*)(ws + 57737216);  // 512 KB (32 slabs x 1024)
  unsigned*       gmaxK = (unsigned*)(ws + 58261504);        // 16 KB -> end ~58.3 MB

  k_prep<<<288, 256, 0, stream>>>(pc, G1, G2, pts4, G1KM, G2KM, gmaxK);
  k_AL<<<1152, 256, 0, stream>>>(pts4, qp, pA, pc, W1, b1, W2, b2, lfT, lfBKM);
  k_BG<<<768, 512, 0, stream>>>(lfBKM, G1KM, g1b, G2KM, gmaxK, pts4, qp, pA, pd2, pi2);
  k_knnC<<<128, 256, 0, stream>>>(pd2, pi2, ids);
  k_out<<<33280, 256, 0, stream>>>(gmaxK, g2b, lfT, ids, out);
}